// Round 7
// baseline (1931.457 us; speedup 1.0000x reference)
//
#include <hip/hip_runtime.h>
#include <hip/hip_bf16.h>

typedef float f32x4 __attribute__((ext_vector_type(4)));
typedef __bf16 bf16x8 __attribute__((ext_vector_type(8)));
typedef __bf16 bf16x4 __attribute__((ext_vector_type(4)));
typedef unsigned short ushort4v __attribute__((ext_vector_type(4)));
typedef unsigned short ushort8v __attribute__((ext_vector_type(8)));

#define MFMA16(a, b, c) __builtin_amdgcn_mfma_f32_16x16x32_bf16((a), (b), (c), 0, 0, 0)

__device__ __forceinline__ unsigned short f2bf(float f) {
    union { float f; unsigned int u; } v; v.f = f;
    unsigned int r = (v.u + 0x7fffu + ((v.u >> 16) & 1u)) >> 16;  // RNE
    return (unsigned short)r;
}

// LDS-only barrier: flush this wave's LDS ops, then s_barrier (no vmcnt drain).
__device__ __forceinline__ void ldsbar() {
    asm volatile("s_waitcnt lgkmcnt(0)" ::: "memory");
    __builtin_amdgcn_s_barrier();
}

// ---------------------------------------------------------------------------
// Fused projection kernel, fp32 E direct (no bf16 pre-pass).
// Grid (128, 3), 512 threads = 8 waves (2 row x 4 col).
//  by==0: Q|K fused (BN=128: cols 0-63 Q, 64-127 K), E read once.
//  by==1,2: V chunk (BN=256), output transposed Vt[b][c][n].
// Tile BM=128 x BN, BK=32, K=512.
// ---------------------------------------------------------------------------
__global__ __launch_bounds__(512) void proj_kernel(const float* __restrict__ E,
        const float* __restrict__ wq, const float* __restrict__ bq, unsigned short* __restrict__ Qb,
        const float* __restrict__ wk, const float* __restrict__ bk, unsigned short* __restrict__ Kb,
        const float* __restrict__ wv, const float* __restrict__ bv, unsigned short* __restrict__ Vt)
{
    __shared__ __align__(16) unsigned short Al[128][40];
    __shared__ __align__(16) unsigned short Bl[256][40];

    const int tid = threadIdx.x;
    const int w = tid >> 6, l = tid & 63, g = l >> 4, li = l & 15;
    const int wm = w >> 2, wn = w & 3;   // 2 x 4 waves
    const int bx = blockIdx.x, by = blockIdx.y;
    const bool isQK = (by == 0);
    const int BN = isQK ? 128 : 256;
    const int NB = isQK ? 2 : 4;         // 16-col frags per wave
    const int row0 = bx * 128;
    const int c0v = (by - 1) * 256;      // V chunk base (by>=1)

    f32x4 acc[4][4];
#pragma unroll
    for (int mb = 0; mb < 4; ++mb)
#pragma unroll
        for (int nb = 0; nb < 4; ++nb) acc[mb][nb] = (f32x4)0.0f;

    const int arow = tid >> 2;           // 0..127
    const int ak = (tid & 3) * 8;        // 0,8,16,24

    for (int kt = 0; kt < 16; ++kt) {
        const int k0 = kt * 32;
        // stage A: E fp32 -> bf16 [128][32]
        {
            const float* ep = &E[(size_t)(row0 + arow) * 512 + k0 + ak];
            f32x4 v0 = *(const f32x4*)ep;
            f32x4 v1 = *(const f32x4*)(ep + 4);
            ushort8v u;
#pragma unroll
            for (int j = 0; j < 4; ++j) { u[j] = f2bf(v0[j]); u[4 + j] = f2bf(v1[j]); }
            *(ushort8v*)&Al[arow][ak] = u;
        }
        // stage B transposed: Bl[c][k] = W[k0+k][c]
        if (isQK) {
            // 128 cols: 32 f32x4 per k-row, 16 k-rows per pass, 2 passes
#pragma unroll
            for (int i = 0; i < 2; ++i) {
                const int kk = (tid >> 5) + 16 * i;
                const int cc = (tid & 31) * 4;
                const float* wsrc = (cc < 64) ? &wq[(size_t)(k0 + kk) * 64 + cc]
                                              : &wk[(size_t)(k0 + kk) * 64 + (cc - 64)];
                f32x4 v = *(const f32x4*)wsrc;
#pragma unroll
                for (int j = 0; j < 4; ++j) Bl[cc + j][kk] = f2bf(v[j]);
            }
        } else {
            // 256 cols: 64 f32x4 per k-row, 8 k-rows per pass, 4 passes
#pragma unroll
            for (int i = 0; i < 4; ++i) {
                const int kk = (tid >> 6) + 8 * i;
                const int cc = (tid & 63) * 4;
                f32x4 v = *(const f32x4*)&wv[(size_t)(k0 + kk) * 512 + c0v + cc];
#pragma unroll
                for (int j = 0; j < 4; ++j) Bl[cc + j][kk] = f2bf(v[j]);
            }
        }
        __syncthreads();

        bf16x8 af[4], bw[4];
#pragma unroll
        for (int mb = 0; mb < 4; ++mb) af[mb] = *(const bf16x8*)&Al[wm * 64 + mb * 16 + li][8 * g];
        for (int nb = 0; nb < NB; ++nb)
            bw[nb] = *(const bf16x8*)&Bl[wn * (BN / 4) + nb * 16 + li][8 * g];
#pragma unroll
        for (int mb = 0; mb < 4; ++mb)
            for (int nb = 0; nb < NB; ++nb) acc[mb][nb] = MFMA16(af[mb], bw[nb], acc[mb][nb]);
        __syncthreads();
    }

    // epilogue
#pragma unroll
    for (int mb = 0; mb < 4; ++mb) {
        for (int nb = 0; nb < NB; ++nb) {
            const int coll = wn * (BN / 4) + nb * 16 + li;   // 0..BN-1
            const int grow0 = row0 + wm * 64 + mb * 16 + 4 * g;
            if (isQK) {
                if (coll < 64) {
                    const float bb = bq[coll];
#pragma unroll
                    for (int r = 0; r < 4; ++r)
                        Qb[(size_t)(grow0 + r) * 64 + coll] = f2bf((acc[mb][nb][r] + bb) * 0.125f);
                } else {
                    const float bb = bk[coll - 64];
#pragma unroll
                    for (int r = 0; r < 4; ++r)
                        Kb[(size_t)(grow0 + r) * 64 + (coll - 64)] = f2bf(acc[mb][nb][r] + bb);
                }
            } else {
                const int col = c0v + coll;
                const float bb = bv[col];
                ushort4v u;
#pragma unroll
                for (int r = 0; r < 4; ++r) u[r] = f2bf(acc[mb][nb][r] + bb);
                const int bbatch = grow0 >> 12, n = grow0 & 4095;
                *(ushort4v*)(Vt + ((size_t)bbatch * 512 + col) * 4096 + n) = u;
            }
        }
    }
}

// ---------------------------------------------------------------------------
// Causal flash attention, v7: K direct from global (no K LDS staging).
// With swapped QK^T, the K A-fragment is a contiguous 16B global load
// (L1/L2-resident, coalesced) -- removing Kl kills ~35% of the LDS-pipe
// cycles that bound v6. Dual-stream (2x64 kv/iter), V reg loads,
// non-draining barriers, qt-paired dispatch, setprio on MFMA clusters.
// ---------------------------------------------------------------------------
__global__ __launch_bounds__(512) void attn_kernel(const unsigned short* __restrict__ Qb,
                                                   const unsigned short* __restrict__ Kb,
                                                   const unsigned short* __restrict__ Vt,
                                                   float* __restrict__ out)
{
    __shared__ __align__(16) unsigned short Pl[2][64][72];  // [grp][q][kv]
    __shared__ float pm2[2][64];
    __shared__ float rs2[64];
    __shared__ float scl_l[64];
    __shared__ float lsum_l[64];

    const int tid = threadIdx.x;
    const int w = tid >> 6, l = tid & 63, g = l >> 4, li = l & 15;
    const int grp = w >> 2, wq4 = w & 3;
    const int bid = blockIdx.x;
    const int t = bid >> 3, b = (bid >> 1) & 3, ch = bid & 1;
    const int qt = (t < 32) ? (63 - t) : (t - 32);
    const int q0 = qt * 64;
    const int niter = (qt >> 1) + 1;
    const int qrow = 16 * wq4 + li;  // tile-local q row owned by this lane in phase A

    const unsigned short* qptr = Qb + ((size_t)(b * 4096 + q0 + qrow)) * 64 + 8 * g;
    const bf16x8 QA0 = *(const bf16x8*)qptr;
    const bf16x8 QA1 = *(const bf16x8*)(qptr + 32);

    float m_r = -INFINITY, l_r = 0.0f;

    f32x4 Of[4][2];
#pragma unroll
    for (int qb = 0; qb < 4; ++qb) { Of[qb][0] = (f32x4)0.0f; Of[qb][1] = (f32x4)0.0f; }

    const int cglob = ch * 256 + w * 32 + li;
    const unsigned short* vb2 = Vt + ((size_t)(b * 512 + cglob)) * 4096 + 8 * g;
    const unsigned short* kbase = Kb + ((size_t)(b * 4096 + li)) * 64 + 8 * g;

    for (int k = 0; k < niter; ++k) {
        const int tA = 2 * k, tB = 2 * k + 1;
        const bool actB = (tB <= qt);
        const int myt = grp ? tB : tA;
        const bool act = grp ? actB : true;

        const size_t kvA = (size_t)tA * 64;
        const size_t kvB = (size_t)tB * 64;   // only used when actB
        const size_t kvMy = (size_t)myt * 64;

        // ---- issue K frags (global, L1/L2-hot) + VA loads ----
        bf16x8 KA[4][2];
        if (act) {
#pragma unroll
            for (int cb = 0; cb < 4; ++cb)
#pragma unroll
                for (int ks = 0; ks < 2; ++ks)
                    KA[cb][ks] = *(const bf16x8*)(kbase + (kvMy + cb * 16) * 64 + ks * 32);
        }
        bf16x8 VA[2][2];
#pragma unroll
        for (int cf = 0; cf < 2; ++cf)
#pragma unroll
            for (int ks = 0; ks < 2; ++ks)
                VA[cf][ks] = *(const bf16x8*)(vb2 + (size_t)cf * 16 * 4096 + kvA + ks * 32);

        // ---- phase A (swapped): S^T[kv][q], kv lane-local ----
        f32x4 S[4];
        float pm;
        if (act) {
            __builtin_amdgcn_s_setprio(1);
#pragma unroll
            for (int cb = 0; cb < 4; ++cb) {
                f32x4 s = (f32x4)0.0f;
                s = MFMA16(KA[cb][0], QA0, s);   // A = K, B = Q  ->  D = S^T
                s = MFMA16(KA[cb][1], QA1, s);
                S[cb] = s;
            }
            __builtin_amdgcn_s_setprio(0);
        }
        // VB loads issued after phase A (KA regs dead -> keeps VGPR peak <=128)
        bf16x8 VBt[2][2];
        if (actB) {
#pragma unroll
            for (int cf = 0; cf < 2; ++cf)
#pragma unroll
                for (int ks = 0; ks < 2; ++ks)
                    VBt[cf][ks] = *(const bf16x8*)(vb2 + (size_t)cf * 16 * 4096 + kvB + ks * 32);
        }
        if (act) {
            if (myt == qt) {  // diagonal tile: mask kv > q
#pragma unroll
                for (int cb = 0; cb < 4; ++cb)
#pragma unroll
                    for (int r = 0; r < 4; ++r)
                        if (cb * 16 + 4 * g + r > qrow) S[cb][r] = -1e30f;
            }
            f32x4 m4 = S[0];
#pragma unroll
            for (int cb = 1; cb < 4; ++cb)
#pragma unroll
                for (int r = 0; r < 4; ++r) m4[r] = fmaxf(m4[r], S[cb][r]);
            pm = fmaxf(fmaxf(m4[0], m4[1]), fmaxf(m4[2], m4[3]));
            pm = fmaxf(pm, __shfl_xor(pm, 16));
            pm = fmaxf(pm, __shfl_xor(pm, 32));
        } else {
            pm = -INFINITY;
        }
        if (g == 0) pm2[grp][qrow] = pm;
        ldsbar();  // barrier 1 (LDS-only)

        const float mn = fmaxf(m_r, fmaxf(pm2[0][qrow], pm2[1][qrow]));
        const float sc = __expf(m_r - mn);
        m_r = mn;
        if (grp == 0 && g == 0) scl_l[qrow] = sc;

        float rs = 0.0f;
        if (act) {
#pragma unroll
            for (int cb = 0; cb < 4; ++cb) {
                bf16x4 pk;
#pragma unroll
                for (int r = 0; r < 4; ++r) {
                    const float pv = __expf(S[cb][r] - mn);
                    rs += pv;
                    pk[r] = (__bf16)pv;
                }
                *(bf16x4*)&Pl[grp][qrow][cb * 16 + 4 * g] = pk;  // ds_write_b64
            }
            rs += __shfl_xor(rs, 16);
            rs += __shfl_xor(rs, 32);
        }
        if (grp == 1 && g == 0) rs2[qrow] = rs;
        ldsbar();  // barrier 2 (LDS-only)

        if (grp == 0) l_r = l_r * sc + rs + rs2[qrow];

        // ---- phase B: PV ----
        __builtin_amdgcn_s_setprio(1);
#pragma unroll
        for (int qb = 0; qb < 4; ++qb) {
            f32x4 scv = *(const f32x4*)&scl_l[qb * 16 + 4 * g];
            bf16x8 PA0 = *(const bf16x8*)&Pl[0][qb * 16 + li][8 * g];
            bf16x8 PA1 = *(const bf16x8*)&Pl[0][qb * 16 + li][32 + 8 * g];
#pragma unroll
            for (int cf = 0; cf < 2; ++cf) {
                f32x4 o = Of[qb][cf];
#pragma unroll
                for (int r = 0; r < 4; ++r) o[r] *= scv[r];
                o = MFMA16(PA0, VA[cf][0], o);
                o = MFMA16(PA1, VA[cf][1], o);
                Of[qb][cf] = o;
            }
            if (actB) {
                bf16x8 PB0 = *(const bf16x8*)&Pl[1][qb * 16 + li][8 * g];
                bf16x8 PB1 = *(const bf16x8*)&Pl[1][qb * 16 + li][32 + 8 * g];
#pragma unroll
                for (int cf = 0; cf < 2; ++cf) {
                    f32x4 o = Of[qb][cf];
                    o = MFMA16(PB0, VBt[cf][0], o);
                    o = MFMA16(PB1, VBt[cf][1], o);
                    Of[qb][cf] = o;
                }
            }
        }
        __builtin_amdgcn_s_setprio(0);
    }

    if (grp == 0 && g == 0) lsum_l[qrow] = l_r;
    ldsbar();

    float* obase = out + (size_t)(b * 4096 + q0 + 4 * g) * 512 + cglob;
#pragma unroll
    for (int qb = 0; qb < 4; ++qb) {
        f32x4 lv = *(const f32x4*)&lsum_l[qb * 16 + 4 * g];
#pragma unroll
        for (int cf = 0; cf < 2; ++cf)
#pragma unroll
            for (int r = 0; r < 4; ++r)
                obase[(size_t)(qb * 16 + r) * 512 + cf * 16] = Of[qb][cf][r] / lv[r];
    }
}

// ---------------------------------------------------------------------------
extern "C" void kernel_launch(void* const* d_in, const int* in_sizes, int n_in,
                              void* d_out, int out_size, void* d_ws, size_t ws_size,
                              hipStream_t stream)
{
    (void)in_sizes; (void)n_in; (void)out_size; (void)ws_size;
    const float* E  = (const float*)d_in[0];
    const float* wq = (const float*)d_in[2];
    const float* bq = (const float*)d_in[3];
    const float* wk = (const float*)d_in[4];
    const float* bk = (const float*)d_in[5];
    const float* wv = (const float*)d_in[6];
    const float* bv = (const float*)d_in[7];

    const size_t qk_elems = (size_t)4 * 4096 * 64;

    unsigned short* Qb = (unsigned short*)d_ws;                 // [4][4096][64] bf16 (x0.125)
    unsigned short* Kb = Qb + qk_elems;                         // [4][4096][64] bf16
    unsigned short* Vt = Kb + qk_elems;                         // [4][512][4096] bf16 (transposed)
    float* out = (float*)d_out;

    proj_kernel<<<dim3(128, 3), 512, 0, stream>>>(E, wq, bq, Qb, wk, bk, Kb, wv, bv, Vt);
    attn_kernel<<<dim3(512), 512, 0, stream>>>(Qb, Kb, Vt, out);
}

// Round 8
// 238.628 us; speedup vs baseline: 8.0940x; 8.0940x over previous
//
#include <hip/hip_runtime.h>
#include <hip/hip_bf16.h>

typedef float f32x4 __attribute__((ext_vector_type(4)));
typedef __bf16 bf16x8 __attribute__((ext_vector_type(8)));
typedef __bf16 bf16x4 __attribute__((ext_vector_type(4)));
typedef unsigned short ushort4v __attribute__((ext_vector_type(4)));
typedef unsigned short ushort8v __attribute__((ext_vector_type(8)));

#define MFMA16(a, b, c) __builtin_amdgcn_mfma_f32_16x16x32_bf16((a), (b), (c), 0, 0, 0)

__device__ __forceinline__ unsigned short f2bf(float f) {
    union { float f; unsigned int u; } v; v.f = f;
    unsigned int r = (v.u + 0x7fffu + ((v.u >> 16) & 1u)) >> 16;  // RNE
    return (unsigned short)r;
}

// LDS-only barrier: flush this wave's LDS ops, then s_barrier (no vmcnt drain).
__device__ __forceinline__ void ldsbar() {
    asm volatile("s_waitcnt lgkmcnt(0)" ::: "memory");
    __builtin_amdgcn_s_barrier();
}

// ---------------------------------------------------------------------------
// Projection bodies: ALL loop bounds compile-time (round-7 lesson: runtime NB
// put acc/bw in scratch -> 680 MB/dispatch spill traffic, 1800 us).
// 512 threads = 8 waves (2 row x 4 col). BM=128, BK=32, K=512.
// ---------------------------------------------------------------------------
__device__ __forceinline__ void stage_A(const float* __restrict__ E,
                                        unsigned short (*Al)[40], int row0, int k0, int tid)
{
    const int arow = tid >> 2;
    const int ak = (tid & 3) * 8;
    const float* ep = &E[(size_t)(row0 + arow) * 512 + k0 + ak];
    f32x4 v0 = *(const f32x4*)ep;
    f32x4 v1 = *(const f32x4*)(ep + 4);
    ushort8v u;
#pragma unroll
    for (int j = 0; j < 4; ++j) { u[j] = f2bf(v0[j]); u[4 + j] = f2bf(v1[j]); }
    *(ushort8v*)&Al[arow][ak] = u;
}

// QK fused: BN=128 (cols 0-63 Q, 64-127 K), NB=2.
__device__ __forceinline__ void proj_qk_body(const float* __restrict__ E,
        const float* __restrict__ wq, const float* __restrict__ bq, unsigned short* __restrict__ Qb,
        const float* __restrict__ wk, const float* __restrict__ bk, unsigned short* __restrict__ Kb,
        unsigned short (*Al)[40], unsigned short (*Bl)[40], int bx)
{
    const int tid = threadIdx.x;
    const int w = tid >> 6, l = tid & 63, g = l >> 4, li = l & 15;
    const int wm = w >> 2, wn = w & 3;
    const int row0 = bx * 128;

    f32x4 acc[4][2];
#pragma unroll
    for (int mb = 0; mb < 4; ++mb)
#pragma unroll
        for (int nb = 0; nb < 2; ++nb) acc[mb][nb] = (f32x4)0.0f;

    for (int kt = 0; kt < 16; ++kt) {
        const int k0 = kt * 32;
        stage_A(E, Al, row0, k0, tid);
#pragma unroll
        for (int i = 0; i < 2; ++i) {
            const int kk = (tid >> 5) + 16 * i;
            const int cc = (tid & 31) * 4;
            const float* wsrc = (cc < 64) ? &wq[(size_t)(k0 + kk) * 64 + cc]
                                          : &wk[(size_t)(k0 + kk) * 64 + (cc - 64)];
            f32x4 v = *(const f32x4*)wsrc;
#pragma unroll
            for (int j = 0; j < 4; ++j) Bl[cc + j][kk] = f2bf(v[j]);
        }
        __syncthreads();

        bf16x8 af[4], bw[2];
#pragma unroll
        for (int mb = 0; mb < 4; ++mb) af[mb] = *(const bf16x8*)&Al[wm * 64 + mb * 16 + li][8 * g];
#pragma unroll
        for (int nb = 0; nb < 2; ++nb)
            bw[nb] = *(const bf16x8*)&Bl[wn * 32 + nb * 16 + li][8 * g];
#pragma unroll
        for (int mb = 0; mb < 4; ++mb)
#pragma unroll
            for (int nb = 0; nb < 2; ++nb) acc[mb][nb] = MFMA16(af[mb], bw[nb], acc[mb][nb]);
        __syncthreads();
    }

#pragma unroll
    for (int mb = 0; mb < 4; ++mb) {
#pragma unroll
        for (int nb = 0; nb < 2; ++nb) {
            const int coll = wn * 32 + nb * 16 + li;
            const int grow0 = row0 + wm * 64 + mb * 16 + 4 * g;
            if (coll < 64) {
                const float bb = bq[coll];
#pragma unroll
                for (int r = 0; r < 4; ++r)
                    Qb[(size_t)(grow0 + r) * 64 + coll] = f2bf((acc[mb][nb][r] + bb) * 0.125f);
            } else {
                const float bb = bk[coll - 64];
#pragma unroll
                for (int r = 0; r < 4; ++r)
                    Kb[(size_t)(grow0 + r) * 64 + (coll - 64)] = f2bf(acc[mb][nb][r] + bb);
            }
        }
    }
}

// V: BN=256, NB=4, output transposed Vt[b][c][n].
__device__ __forceinline__ void proj_v_body(const float* __restrict__ E,
        const float* __restrict__ wv, const float* __restrict__ bv, unsigned short* __restrict__ Vt,
        unsigned short (*Al)[40], unsigned short (*Bl)[40], int bx, int vy)
{
    const int tid = threadIdx.x;
    const int w = tid >> 6, l = tid & 63, g = l >> 4, li = l & 15;
    const int wm = w >> 2, wn = w & 3;
    const int row0 = bx * 128;
    const int c0v = vy * 256;

    f32x4 acc[4][4];
#pragma unroll
    for (int mb = 0; mb < 4; ++mb)
#pragma unroll
        for (int nb = 0; nb < 4; ++nb) acc[mb][nb] = (f32x4)0.0f;

    for (int kt = 0; kt < 16; ++kt) {
        const int k0 = kt * 32;
        stage_A(E, Al, row0, k0, tid);
#pragma unroll
        for (int i = 0; i < 4; ++i) {
            const int kk = (tid >> 6) + 8 * i;
            const int cc = (tid & 63) * 4;
            f32x4 v = *(const f32x4*)&wv[(size_t)(k0 + kk) * 512 + c0v + cc];
#pragma unroll
            for (int j = 0; j < 4; ++j) Bl[cc + j][kk] = f2bf(v[j]);
        }
        __syncthreads();

        bf16x8 af[4], bw[4];
#pragma unroll
        for (int mb = 0; mb < 4; ++mb) af[mb] = *(const bf16x8*)&Al[wm * 64 + mb * 16 + li][8 * g];
#pragma unroll
        for (int nb = 0; nb < 4; ++nb)
            bw[nb] = *(const bf16x8*)&Bl[wn * 64 + nb * 16 + li][8 * g];
#pragma unroll
        for (int mb = 0; mb < 4; ++mb)
#pragma unroll
            for (int nb = 0; nb < 4; ++nb) acc[mb][nb] = MFMA16(af[mb], bw[nb], acc[mb][nb]);
        __syncthreads();
    }

#pragma unroll
    for (int mb = 0; mb < 4; ++mb) {
#pragma unroll
        for (int nb = 0; nb < 4; ++nb) {
            const int col = c0v + wn * 64 + nb * 16 + li;
            const int grow0 = row0 + wm * 64 + mb * 16 + 4 * g;
            const float bb = bv[col];
            ushort4v u;
#pragma unroll
            for (int r = 0; r < 4; ++r) u[r] = f2bf(acc[mb][nb][r] + bb);
            const int bbatch = grow0 >> 12, n = grow0 & 4095;
            *(ushort4v*)(Vt + ((size_t)bbatch * 512 + col) * 4096 + n) = u;
        }
    }
}

__global__ __launch_bounds__(512) void proj_kernel(const float* __restrict__ E,
        const float* __restrict__ wq, const float* __restrict__ bq, unsigned short* __restrict__ Qb,
        const float* __restrict__ wk, const float* __restrict__ bk, unsigned short* __restrict__ Kb,
        const float* __restrict__ wv, const float* __restrict__ bv, unsigned short* __restrict__ Vt)
{
    __shared__ __align__(16) unsigned short Al[128][40];
    __shared__ __align__(16) unsigned short Bl[256][40];
    if (blockIdx.y == 0)
        proj_qk_body(E, wq, bq, Qb, wk, bk, Kb, Al, Bl, blockIdx.x);
    else
        proj_v_body(E, wv, bv, Vt, Al, Bl, blockIdx.x, blockIdx.y - 1);
}

// ---------------------------------------------------------------------------
// Causal flash attention, v7 (unchanged from round 7 -- clean measurement):
// K direct from global (no K LDS staging), swapped QK^T, dual-stream,
// V reg loads, non-draining barriers, qt-paired dispatch, setprio.
// ---------------------------------------------------------------------------
__global__ __launch_bounds__(512) void attn_kernel(const unsigned short* __restrict__ Qb,
                                                   const unsigned short* __restrict__ Kb,
                                                   const unsigned short* __restrict__ Vt,
                                                   float* __restrict__ out)
{
    __shared__ __align__(16) unsigned short Pl[2][64][72];  // [grp][q][kv]
    __shared__ float pm2[2][64];
    __shared__ float rs2[64];
    __shared__ float scl_l[64];
    __shared__ float lsum_l[64];

    const int tid = threadIdx.x;
    const int w = tid >> 6, l = tid & 63, g = l >> 4, li = l & 15;
    const int grp = w >> 2, wq4 = w & 3;
    const int bid = blockIdx.x;
    const int t = bid >> 3, b = (bid >> 1) & 3, ch = bid & 1;
    const int qt = (t < 32) ? (63 - t) : (t - 32);
    const int q0 = qt * 64;
    const int niter = (qt >> 1) + 1;
    const int qrow = 16 * wq4 + li;

    const unsigned short* qptr = Qb + ((size_t)(b * 4096 + q0 + qrow)) * 64 + 8 * g;
    const bf16x8 QA0 = *(const bf16x8*)qptr;
    const bf16x8 QA1 = *(const bf16x8*)(qptr + 32);

    float m_r = -INFINITY, l_r = 0.0f;

    f32x4 Of[4][2];
#pragma unroll
    for (int qb = 0; qb < 4; ++qb) { Of[qb][0] = (f32x4)0.0f; Of[qb][1] = (f32x4)0.0f; }

    const int cglob = ch * 256 + w * 32 + li;
    const unsigned short* vb2 = Vt + ((size_t)(b * 512 + cglob)) * 4096 + 8 * g;
    const unsigned short* kbase = Kb + ((size_t)(b * 4096 + li)) * 64 + 8 * g;

    for (int k = 0; k < niter; ++k) {
        const int tA = 2 * k, tB = 2 * k + 1;
        const bool actB = (tB <= qt);
        const int myt = grp ? tB : tA;
        const bool act = grp ? actB : true;

        const size_t kvA = (size_t)tA * 64;
        const size_t kvB = (size_t)tB * 64;
        const size_t kvMy = (size_t)myt * 64;

        bf16x8 KA[4][2];
        if (act) {
#pragma unroll
            for (int cb = 0; cb < 4; ++cb)
#pragma unroll
                for (int ks = 0; ks < 2; ++ks)
                    KA[cb][ks] = *(const bf16x8*)(kbase + (kvMy + cb * 16) * 64 + ks * 32);
        }
        bf16x8 VA[2][2];
#pragma unroll
        for (int cf = 0; cf < 2; ++cf)
#pragma unroll
            for (int ks = 0; ks < 2; ++ks)
                VA[cf][ks] = *(const bf16x8*)(vb2 + (size_t)cf * 16 * 4096 + kvA + ks * 32);

        f32x4 S[4];
        float pm;
        if (act) {
            __builtin_amdgcn_s_setprio(1);
#pragma unroll
            for (int cb = 0; cb < 4; ++cb) {
                f32x4 s = (f32x4)0.0f;
                s = MFMA16(KA[cb][0], QA0, s);   // A = K, B = Q  ->  D = S^T
                s = MFMA16(KA[cb][1], QA1, s);
                S[cb] = s;
            }
            __builtin_amdgcn_s_setprio(0);
        }
        bf16x8 VBt[2][2];
        if (actB) {
#pragma unroll
            for (int cf = 0; cf < 2; ++cf)
#pragma unroll
                for (int ks = 0; ks < 2; ++ks)
                    VBt[cf][ks] = *(const bf16x8*)(vb2 + (size_t)cf * 16 * 4096 + kvB + ks * 32);
        }
        if (act) {
            if (myt == qt) {
#pragma unroll
                for (int cb = 0; cb < 4; ++cb)
#pragma unroll
                    for (int r = 0; r < 4; ++r)
                        if (cb * 16 + 4 * g + r > qrow) S[cb][r] = -1e30f;
            }
            f32x4 m4 = S[0];
#pragma unroll
            for (int cb = 1; cb < 4; ++cb)
#pragma unroll
                for (int r = 0; r < 4; ++r) m4[r] = fmaxf(m4[r], S[cb][r]);
            pm = fmaxf(fmaxf(m4[0], m4[1]), fmaxf(m4[2], m4[3]));
            pm = fmaxf(pm, __shfl_xor(pm, 16));
            pm = fmaxf(pm, __shfl_xor(pm, 32));
        } else {
            pm = -INFINITY;
        }
        if (g == 0) pm2[grp][qrow] = pm;
        ldsbar();  // barrier 1

        const float mn = fmaxf(m_r, fmaxf(pm2[0][qrow], pm2[1][qrow]));
        const float sc = __expf(m_r - mn);
        m_r = mn;
        if (grp == 0 && g == 0) scl_l[qrow] = sc;

        float rs = 0.0f;
        if (act) {
#pragma unroll
            for (int cb = 0; cb < 4; ++cb) {
                bf16x4 pk;
#pragma unroll
                for (int r = 0; r < 4; ++r) {
                    const float pv = __expf(S[cb][r] - mn);
                    rs += pv;
                    pk[r] = (__bf16)pv;
                }
                *(bf16x4*)&Pl[grp][qrow][cb * 16 + 4 * g] = pk;
            }
            rs += __shfl_xor(rs, 16);
            rs += __shfl_xor(rs, 32);
        }
        if (grp == 1 && g == 0) rs2[qrow] = rs;
        ldsbar();  // barrier 2

        if (grp == 0) l_r = l_r * sc + rs + rs2[qrow];

        __builtin_amdgcn_s_setprio(1);
#pragma unroll
        for (int qb = 0; qb < 4; ++qb) {
            f32x4 scv = *(const f32x4*)&scl_l[qb * 16 + 4 * g];
            bf16x8 PA0 = *(const bf16x8*)&Pl[0][qb * 16 + li][8 * g];
            bf16x8 PA1 = *(const bf16x8*)&Pl[0][qb * 16 + li][32 + 8 * g];
#pragma unroll
            for (int cf = 0; cf < 2; ++cf) {
                f32x4 o = Of[qb][cf];
#pragma unroll
                for (int r = 0; r < 4; ++r) o[r] *= scv[r];
                o = MFMA16(PA0, VA[cf][0], o);
                o = MFMA16(PA1, VA[cf][1], o);
                Of[qb][cf] = o;
            }
            if (actB) {
                bf16x8 PB0 = *(const bf16x8*)&Pl[1][qb * 16 + li][8 * g];
                bf16x8 PB1 = *(const bf16x8*)&Pl[1][qb * 16 + li][32 + 8 * g];
#pragma unroll
                for (int cf = 0; cf < 2; ++cf) {
                    f32x4 o = Of[qb][cf];
                    o = MFMA16(PB0, VBt[cf][0], o);
                    o = MFMA16(PB1, VBt[cf][1], o);
                    Of[qb][cf] = o;
                }
            }
        }
        __builtin_amdgcn_s_setprio(0);
    }

    if (grp == 0 && g == 0) lsum_l[qrow] = l_r;
    ldsbar();

    float* obase = out + (size_t)(b * 4096 + q0 + 4 * g) * 512 + cglob;
#pragma unroll
    for (int qb = 0; qb < 4; ++qb) {
        f32x4 lv = *(const f32x4*)&lsum_l[qb * 16 + 4 * g];
#pragma unroll
        for (int cf = 0; cf < 2; ++cf)
#pragma unroll
            for (int r = 0; r < 4; ++r)
                obase[(size_t)(qb * 16 + r) * 512 + cf * 16] = Of[qb][cf][r] / lv[r];
    }
}

// ---------------------------------------------------------------------------
extern "C" void kernel_launch(void* const* d_in, const int* in_sizes, int n_in,
                              void* d_out, int out_size, void* d_ws, size_t ws_size,
                              hipStream_t stream)
{
    (void)in_sizes; (void)n_in; (void)out_size; (void)ws_size;
    const float* E  = (const float*)d_in[0];
    const float* wq = (const float*)d_in[2];
    const float* bq = (const float*)d_in[3];
    const float* wk = (const float*)d_in[4];
    const float* bk = (const float*)d_in[5];
    const float* wv = (const float*)d_in[6];
    const float* bv = (const float*)d_in[7];

    const size_t qk_elems = (size_t)4 * 4096 * 64;

    unsigned short* Qb = (unsigned short*)d_ws;                 // [4][4096][64] bf16 (x0.125)
    unsigned short* Kb = Qb + qk_elems;                         // [4][4096][64] bf16
    unsigned short* Vt = Kb + qk_elems;                         // [4][512][4096] bf16 (transposed)
    float* out = (float*)d_out;

    proj_kernel<<<dim3(128, 3), 512, 0, stream>>>(E, wq, bq, Qb, wk, bk, Kb, wv, bv, Vt);
    attn_kernel<<<dim3(512), 512, 0, stream>>>(Qb, Kb, Vt, out);
}

// Round 9
// 228.241 us; speedup vs baseline: 8.4624x; 1.0455x over previous
//
#include <hip/hip_runtime.h>
#include <hip/hip_bf16.h>

typedef float f32x4 __attribute__((ext_vector_type(4)));
typedef __bf16 bf16x8 __attribute__((ext_vector_type(8)));
typedef __bf16 bf16x4 __attribute__((ext_vector_type(4)));
typedef unsigned short ushort4v __attribute__((ext_vector_type(4)));
typedef unsigned short ushort8v __attribute__((ext_vector_type(8)));

#define MFMA16(a, b, c) __builtin_amdgcn_mfma_f32_16x16x32_bf16((a), (b), (c), 0, 0, 0)

__device__ __forceinline__ unsigned short f2bf(float f) {
    union { float f; unsigned int u; } v; v.f = f;
    unsigned int r = (v.u + 0x7fffu + ((v.u >> 16) & 1u)) >> 16;  // RNE
    return (unsigned short)r;
}
__device__ __forceinline__ int imin(int a, int b) { return a < b ? a : b; }

// LDS-only barrier: flush this wave's LDS ops, then s_barrier (no vmcnt drain).
__device__ __forceinline__ void ldsbar() {
    asm volatile("s_waitcnt lgkmcnt(0)" ::: "memory");
    __builtin_amdgcn_s_barrier();
}

// ---------------------------------------------------------------------------
// Projection bodies: ALL loop bounds compile-time (round-7 lesson: runtime NB
// put acc/bw in scratch -> 680 MB/dispatch spill traffic, 1800 us).
// 512 threads = 8 waves (2 row x 4 col). BM=128, BK=32, K=512.
// ---------------------------------------------------------------------------
__device__ __forceinline__ void stage_A(const float* __restrict__ E,
                                        unsigned short (*Al)[40], int row0, int k0, int tid)
{
    const int arow = tid >> 2;
    const int ak = (tid & 3) * 8;
    const float* ep = &E[(size_t)(row0 + arow) * 512 + k0 + ak];
    f32x4 v0 = *(const f32x4*)ep;
    f32x4 v1 = *(const f32x4*)(ep + 4);
    ushort8v u;
#pragma unroll
    for (int j = 0; j < 4; ++j) { u[j] = f2bf(v0[j]); u[4 + j] = f2bf(v1[j]); }
    *(ushort8v*)&Al[arow][ak] = u;
}

// QK fused: BN=128 (cols 0-63 Q, 64-127 K), NB=2.
__device__ __forceinline__ void proj_qk_body(const float* __restrict__ E,
        const float* __restrict__ wq, const float* __restrict__ bq, unsigned short* __restrict__ Qb,
        const float* __restrict__ wk, const float* __restrict__ bk, unsigned short* __restrict__ Kb,
        unsigned short (*Al)[40], unsigned short (*Bl)[40], int bx)
{
    const int tid = threadIdx.x;
    const int w = tid >> 6, l = tid & 63, g = l >> 4, li = l & 15;
    const int wm = w >> 2, wn = w & 3;
    const int row0 = bx * 128;

    f32x4 acc[4][2];
#pragma unroll
    for (int mb = 0; mb < 4; ++mb)
#pragma unroll
        for (int nb = 0; nb < 2; ++nb) acc[mb][nb] = (f32x4)0.0f;

    for (int kt = 0; kt < 16; ++kt) {
        const int k0 = kt * 32;
        stage_A(E, Al, row0, k0, tid);
#pragma unroll
        for (int i = 0; i < 2; ++i) {
            const int kk = (tid >> 5) + 16 * i;
            const int cc = (tid & 31) * 4;
            const float* wsrc = (cc < 64) ? &wq[(size_t)(k0 + kk) * 64 + cc]
                                          : &wk[(size_t)(k0 + kk) * 64 + (cc - 64)];
            f32x4 v = *(const f32x4*)wsrc;
#pragma unroll
            for (int j = 0; j < 4; ++j) Bl[cc + j][kk] = f2bf(v[j]);
        }
        __syncthreads();

        bf16x8 af[4], bw[2];
#pragma unroll
        for (int mb = 0; mb < 4; ++mb) af[mb] = *(const bf16x8*)&Al[wm * 64 + mb * 16 + li][8 * g];
#pragma unroll
        for (int nb = 0; nb < 2; ++nb)
            bw[nb] = *(const bf16x8*)&Bl[wn * 32 + nb * 16 + li][8 * g];
#pragma unroll
        for (int mb = 0; mb < 4; ++mb)
#pragma unroll
            for (int nb = 0; nb < 2; ++nb) acc[mb][nb] = MFMA16(af[mb], bw[nb], acc[mb][nb]);
        __syncthreads();
    }

#pragma unroll
    for (int mb = 0; mb < 4; ++mb) {
#pragma unroll
        for (int nb = 0; nb < 2; ++nb) {
            const int coll = wn * 32 + nb * 16 + li;
            const int grow0 = row0 + wm * 64 + mb * 16 + 4 * g;
            if (coll < 64) {
                const float bb = bq[coll];
#pragma unroll
                for (int r = 0; r < 4; ++r)
                    Qb[(size_t)(grow0 + r) * 64 + coll] = f2bf((acc[mb][nb][r] + bb) * 0.125f);
            } else {
                const float bb = bk[coll - 64];
#pragma unroll
                for (int r = 0; r < 4; ++r)
                    Kb[(size_t)(grow0 + r) * 64 + (coll - 64)] = f2bf(acc[mb][nb][r] + bb);
            }
        }
    }
}

// V: BN=256, NB=4, output transposed Vt[b][c][n].
__device__ __forceinline__ void proj_v_body(const float* __restrict__ E,
        const float* __restrict__ wv, const float* __restrict__ bv, unsigned short* __restrict__ Vt,
        unsigned short (*Al)[40], unsigned short (*Bl)[40], int bx, int vy)
{
    const int tid = threadIdx.x;
    const int w = tid >> 6, l = tid & 63, g = l >> 4, li = l & 15;
    const int wm = w >> 2, wn = w & 3;
    const int row0 = bx * 128;
    const int c0v = vy * 256;

    f32x4 acc[4][4];
#pragma unroll
    for (int mb = 0; mb < 4; ++mb)
#pragma unroll
        for (int nb = 0; nb < 4; ++nb) acc[mb][nb] = (f32x4)0.0f;

    for (int kt = 0; kt < 16; ++kt) {
        const int k0 = kt * 32;
        stage_A(E, Al, row0, k0, tid);
#pragma unroll
        for (int i = 0; i < 4; ++i) {
            const int kk = (tid >> 6) + 8 * i;
            const int cc = (tid & 63) * 4;
            f32x4 v = *(const f32x4*)&wv[(size_t)(k0 + kk) * 512 + c0v + cc];
#pragma unroll
            for (int j = 0; j < 4; ++j) Bl[cc + j][kk] = f2bf(v[j]);
        }
        __syncthreads();

        bf16x8 af[4], bw[4];
#pragma unroll
        for (int mb = 0; mb < 4; ++mb) af[mb] = *(const bf16x8*)&Al[wm * 64 + mb * 16 + li][8 * g];
#pragma unroll
        for (int nb = 0; nb < 4; ++nb)
            bw[nb] = *(const bf16x8*)&Bl[wn * 64 + nb * 16 + li][8 * g];
#pragma unroll
        for (int mb = 0; mb < 4; ++mb)
#pragma unroll
            for (int nb = 0; nb < 4; ++nb) acc[mb][nb] = MFMA16(af[mb], bw[nb], acc[mb][nb]);
        __syncthreads();
    }

#pragma unroll
    for (int mb = 0; mb < 4; ++mb) {
#pragma unroll
        for (int nb = 0; nb < 4; ++nb) {
            const int col = c0v + wn * 64 + nb * 16 + li;
            const int grow0 = row0 + wm * 64 + mb * 16 + 4 * g;
            const float bb = bv[col];
            ushort4v u;
#pragma unroll
            for (int r = 0; r < 4; ++r) u[r] = f2bf(acc[mb][nb][r] + bb);
            const int bbatch = grow0 >> 12, n = grow0 & 4095;
            *(ushort4v*)(Vt + ((size_t)bbatch * 512 + col) * 4096 + n) = u;
        }
    }
}

__global__ __launch_bounds__(512) void proj_kernel(const float* __restrict__ E,
        const float* __restrict__ wq, const float* __restrict__ bq, unsigned short* __restrict__ Qb,
        const float* __restrict__ wk, const float* __restrict__ bk, unsigned short* __restrict__ Kb,
        const float* __restrict__ wv, const float* __restrict__ bv, unsigned short* __restrict__ Vt)
{
    __shared__ __align__(16) unsigned short Al[128][40];
    __shared__ __align__(16) unsigned short Bl[256][40];
    if (blockIdx.y == 0)
        proj_qk_body(E, wq, bq, Qb, wk, bk, Kb, Al, Bl, blockIdx.x);
    else
        proj_v_body(E, wv, bv, Vt, Al, Bl, blockIdx.x, blockIdx.y - 1);
}

// ---------------------------------------------------------------------------
// Causal flash attention, v9: K in registers with ONE-ITERATION PREFETCH.
// KA is reloaded in place for iter k+1 immediately after its last use in
// phase A(k) -- the loads have softmax + 2 barriers + phase B (~2-3K cy)
// to land, hiding the global gather latency that bound v8.
// Swapped QK^T, dual-stream, non-draining barriers, qt-paired, setprio.
// ---------------------------------------------------------------------------
__global__ __launch_bounds__(512) void attn_kernel(const unsigned short* __restrict__ Qb,
                                                   const unsigned short* __restrict__ Kb,
                                                   const unsigned short* __restrict__ Vt,
                                                   float* __restrict__ out)
{
    __shared__ __align__(16) unsigned short Pl[2][64][72];  // [grp][q][kv]
    __shared__ float pm2[2][64];
    __shared__ float rs2[64];
    __shared__ float scl_l[64];
    __shared__ float lsum_l[64];

    const int tid = threadIdx.x;
    const int w = tid >> 6, l = tid & 63, g = l >> 4, li = l & 15;
    const int grp = w >> 2, wq4 = w & 3;
    const int bid = blockIdx.x;
    const int t = bid >> 3, b = (bid >> 1) & 3, ch = bid & 1;
    const int qt = (t < 32) ? (63 - t) : (t - 32);
    const int q0 = qt * 64;
    const int niter = (qt >> 1) + 1;
    const int qrow = 16 * wq4 + li;

    const unsigned short* qptr = Qb + ((size_t)(b * 4096 + q0 + qrow)) * 64 + 8 * g;
    const bf16x8 QA0 = *(const bf16x8*)qptr;
    const bf16x8 QA1 = *(const bf16x8*)(qptr + 32);

    float m_r = -INFINITY, l_r = 0.0f;

    f32x4 Of[4][2];
#pragma unroll
    for (int qb = 0; qb < 4; ++qb) { Of[qb][0] = (f32x4)0.0f; Of[qb][1] = (f32x4)0.0f; }

    const int cglob = ch * 256 + w * 32 + li;
    const unsigned short* vb2 = Vt + ((size_t)(b * 512 + cglob)) * 4096 + 8 * g;
    const unsigned short* kbase = Kb + ((size_t)(b * 4096 + li)) * 64 + 8 * g;

    // prologue: prefetch K fragments for iteration 0 (grp0: tile 0, grp1: tile 1)
    bf16x8 KA[4][2];
    {
        const size_t kv0 = (size_t)imin(grp, qt) * 64;
#pragma unroll
        for (int cb = 0; cb < 4; ++cb)
#pragma unroll
            for (int ks = 0; ks < 2; ++ks)
                KA[cb][ks] = *(const bf16x8*)(kbase + (kv0 + cb * 16) * 64 + ks * 32);
    }

    for (int k = 0; k < niter; ++k) {
        const int tA = 2 * k, tB = 2 * k + 1;
        const bool actB = (tB <= qt);
        const int myt = grp ? tB : tA;
        const bool act = grp ? actB : true;

        const size_t kvA = (size_t)tA * 64;
        const size_t kvB = (size_t)tB * 64;

        bf16x8 VA[2][2];
#pragma unroll
        for (int cf = 0; cf < 2; ++cf)
#pragma unroll
            for (int ks = 0; ks < 2; ++ks)
                VA[cf][ks] = *(const bf16x8*)(vb2 + (size_t)cf * 16 * 4096 + kvA + ks * 32);

        // ---- phase A (swapped) with PREFETCHED K ----
        f32x4 S[4];
        float pm;
        if (act) {
            __builtin_amdgcn_s_setprio(1);
#pragma unroll
            for (int cb = 0; cb < 4; ++cb) {
                f32x4 s = (f32x4)0.0f;
                s = MFMA16(KA[cb][0], QA0, s);   // A = K, B = Q  ->  D = S^T
                s = MFMA16(KA[cb][1], QA1, s);
                S[cb] = s;
            }
            __builtin_amdgcn_s_setprio(0);
        }
        // KA dead: reload in place for iteration k+1 (clamped; harmless overrun)
        {
            const size_t kvn = (size_t)imin(2 * (k + 1) + grp, qt) * 64;
#pragma unroll
            for (int cb = 0; cb < 4; ++cb)
#pragma unroll
                for (int ks = 0; ks < 2; ++ks)
                    KA[cb][ks] = *(const bf16x8*)(kbase + (kvn + cb * 16) * 64 + ks * 32);
        }
        bf16x8 VBt[2][2];
        if (actB) {
#pragma unroll
            for (int cf = 0; cf < 2; ++cf)
#pragma unroll
                for (int ks = 0; ks < 2; ++ks)
                    VBt[cf][ks] = *(const bf16x8*)(vb2 + (size_t)cf * 16 * 4096 + kvB + ks * 32);
        }
        if (act) {
            if (myt == qt) {
#pragma unroll
                for (int cb = 0; cb < 4; ++cb)
#pragma unroll
                    for (int r = 0; r < 4; ++r)
                        if (cb * 16 + 4 * g + r > qrow) S[cb][r] = -1e30f;
            }
            f32x4 m4 = S[0];
#pragma unroll
            for (int cb = 1; cb < 4; ++cb)
#pragma unroll
                for (int r = 0; r < 4; ++r) m4[r] = fmaxf(m4[r], S[cb][r]);
            pm = fmaxf(fmaxf(m4[0], m4[1]), fmaxf(m4[2], m4[3]));
            pm = fmaxf(pm, __shfl_xor(pm, 16));
            pm = fmaxf(pm, __shfl_xor(pm, 32));
        } else {
            pm = -INFINITY;
        }
        if (g == 0) pm2[grp][qrow] = pm;
        ldsbar();  // barrier 1

        const float mn = fmaxf(m_r, fmaxf(pm2[0][qrow], pm2[1][qrow]));
        const float sc = __expf(m_r - mn);
        m_r = mn;
        if (grp == 0 && g == 0) scl_l[qrow] = sc;

        float rs = 0.0f;
        if (act) {
#pragma unroll
            for (int cb = 0; cb < 4; ++cb) {
                bf16x4 pk;
#pragma unroll
                for (int r = 0; r < 4; ++r) {
                    const float pv = __expf(S[cb][r] - mn);
                    rs += pv;
                    pk[r] = (__bf16)pv;
                }
                *(bf16x4*)&Pl[grp][qrow][cb * 16 + 4 * g] = pk;
            }
            rs += __shfl_xor(rs, 16);
            rs += __shfl_xor(rs, 32);
        }
        if (grp == 1 && g == 0) rs2[qrow] = rs;
        ldsbar();  // barrier 2

        if (grp == 0) l_r = l_r * sc + rs + rs2[qrow];

        // ---- phase B: PV ----
        __builtin_amdgcn_s_setprio(1);
#pragma unroll
        for (int qb = 0; qb < 4; ++qb) {
            f32x4 scv = *(const f32x4*)&scl_l[qb * 16 + 4 * g];
            bf16x8 PA0 = *(const bf16x8*)&Pl[0][qb * 16 + li][8 * g];
            bf16x8 PA1 = *(const bf16x8*)&Pl[0][qb * 16 + li][32 + 8 * g];
#pragma unroll
            for (int cf = 0; cf < 2; ++cf) {
                f32x4 o = Of[qb][cf];
#pragma unroll
                for (int r = 0; r < 4; ++r) o[r] *= scv[r];
                o = MFMA16(PA0, VA[cf][0], o);
                o = MFMA16(PA1, VA[cf][1], o);
                Of[qb][cf] = o;
            }
            if (actB) {
                bf16x8 PB0 = *(const bf16x8*)&Pl[1][qb * 16 + li][8 * g];
                bf16x8 PB1 = *(const bf16x8*)&Pl[1][qb * 16 + li][32 + 8 * g];
#pragma unroll
                for (int cf = 0; cf < 2; ++cf) {
                    f32x4 o = Of[qb][cf];
                    o = MFMA16(PB0, VBt[cf][0], o);
                    o = MFMA16(PB1, VBt[cf][1], o);
                    Of[qb][cf] = o;
                }
            }
        }
        __builtin_amdgcn_s_setprio(0);
    }

    if (grp == 0 && g == 0) lsum_l[qrow] = l_r;
    ldsbar();

    float* obase = out + (size_t)(b * 4096 + q0 + 4 * g) * 512 + cglob;
#pragma unroll
    for (int qb = 0; qb < 4; ++qb) {
        f32x4 lv = *(const f32x4*)&lsum_l[qb * 16 + 4 * g];
#pragma unroll
        for (int cf = 0; cf < 2; ++cf)
#pragma unroll
            for (int r = 0; r < 4; ++r)
                obase[(size_t)(qb * 16 + r) * 512 + cf * 16] = Of[qb][cf][r] / lv[r];
    }
}

// ---------------------------------------------------------------------------
extern "C" void kernel_launch(void* const* d_in, const int* in_sizes, int n_in,
                              void* d_out, int out_size, void* d_ws, size_t ws_size,
                              hipStream_t stream)
{
    (void)in_sizes; (void)n_in; (void)out_size; (void)ws_size;
    const float* E  = (const float*)d_in[0];
    const float* wq = (const float*)d_in[2];
    const float* bq = (const float*)d_in[3];
    const float* wk = (const float*)d_in[4];
    const float* bk = (const float*)d_in[5];
    const float* wv = (const float*)d_in[6];
    const float* bv = (const float*)d_in[7];

    const size_t qk_elems = (size_t)4 * 4096 * 64;

    unsigned short* Qb = (unsigned short*)d_ws;                 // [4][4096][64] bf16 (x0.125)
    unsigned short* Kb = Qb + qk_elems;                         // [4][4096][64] bf16
    unsigned short* Vt = Kb + qk_elems;                         // [4][512][4096] bf16 (transposed)
    float* out = (float*)d_out;

    proj_kernel<<<dim3(128, 3), 512, 0, stream>>>(E, wq, bq, Qb, wk, bk, Kb, wv, bv, Vt);
    attn_kernel<<<dim3(512), 512, 0, stream>>>(Qb, Kb, Vt, out);
}